// Round 2
// baseline (473.146 us; speedup 1.0000x reference)
//
#include <hip/hip_runtime.h>
#include <hip/hip_bf16.h>
#include <math.h>

#define NH     4
#define RD     5
#define WW     49
#define DM     256
#define BATCH  32
#define NTOK   4900
#define GSEG   20
#define SEG    245            // WW*RD tokens per segment

typedef short bf16x8 __attribute__((ext_vector_type(8)));
typedef short bf16x4 __attribute__((ext_vector_type(4)));
typedef float f32x4  __attribute__((ext_vector_type(4)));

__device__ __forceinline__ short f2bf(float f) {
    union { __hip_bfloat16 h; short s; } u;
    u.h = __float2bfloat16(f);
    return u.s;
}

// X tile: [64 tokens][256 d], pitch 256, XOR-swizzle on 8-short granules.
__device__ __forceinline__ int qix(int row, int col) {
    return row * 256 + (col ^ ((row & 7) << 3));
}
// XT tile: [256 d][64 tokens], pitch 64, same-style swizzle. Lives after X.
__device__ __forceinline__ int tix(int d, int j) {
    return 64 * 256 + d * 64 + (j ^ ((d & 7) << 3));
}

// ---------------------------------------------------------------------------
// Pre-convert Wq, Wo (fp32 [256,256]) to bf16.
// ---------------------------------------------------------------------------
__global__ __launch_bounds__(256)
void wcvt(const float* __restrict__ Wq, const float* __restrict__ Wo,
          short* __restrict__ Wqb, short* __restrict__ Wob) {
    int t = blockIdx.x * 256 + threadIdx.x;       // 0..32767 float4 units
    const float* src = (t < 16384) ? Wq : Wo;
    short* dst = (t < 16384) ? Wqb : Wob;
    int i = (t & 16383) * 4;
    float4 v = *(const float4*)(src + i);
    bf16x4 o = { f2bf(v.x), f2bf(v.y), f2bf(v.z), f2bf(v.w) };
    *(bf16x4*)(dst + i) = o;
}

// ---------------------------------------------------------------------------
// Fused: one block per (b,g,r) dilation group. 256 threads = 4 waves.
//   Phase 1: X = bf16(emb[49 strided rows] @ Wq^T + bq) -> LDS (X and XT)
//   Phase 2: per-wave head attention, barrier-free; P overwrites X head-slice,
//            then O overwrites P.
//   Phase 3: out = O @ Wo^T + bo -> global fp32
// LDS: X 32 KB + XT 32 KB = 64 KB -> 2 blocks/CU. Only 2 __syncthreads total.
// ---------------------------------------------------------------------------
__global__ __launch_bounds__(256, 2)
void fused(const float* __restrict__ emb, const short* __restrict__ Wqb,
           const float* __restrict__ bq, const short* __restrict__ Wob,
           const float* __restrict__ bo, float* __restrict__ out) {
    __shared__ __align__(16) short sm[64 * 256 + 256 * 64];   // X | XT

    const int tid = threadIdx.x;
    const int wv = tid >> 6, ln = tid & 63, lc = ln & 15, lq = ln >> 4;

    // Bijective chunked XCD swizzle: 3200 = 8 * 400. Consecutive logical
    // blocks (the 5 r's of one (b,g)) land on the same XCD -> shared emb
    // lines hit the same L2.
    const int bid = blockIdx.x;
    const int L = (bid & 7) * 400 + (bid >> 3);
    const int b = L / 100;
    const int rem = L - b * 100;
    const int g = rem / 5, r = rem - (rem / 5) * 5;
    const size_t tok0 = (size_t)b * NTOK + (size_t)g * SEG + r;
    const int n0 = wv * 64;              // wave's 64-col slice (N for GEMMs, head for attn)

    // ================= Phase 1: X = bf16(emb @ Wq^T + bq) =================
    {
        const float* ar[4];
        const short* br[4];
        #pragma unroll
        for (int mi = 0; mi < 4; mi++) {
            int t = mi * 16 + lc;
            t = (t > WW - 1) ? (WW - 1) : t;              // clamp pad rows
            ar[mi] = emb + (tok0 + (size_t)t * RD) * DM + lq * 8;
        }
        #pragma unroll
        for (int ni = 0; ni < 4; ni++)
            br[ni] = Wqb + (size_t)(n0 + ni * 16 + lc) * DM + lq * 8;

        f32x4 acc[4][4] = {};
        for (int k0 = 0; k0 < DM; k0 += 32) {
            bf16x8 af[4], bfr[4];
            #pragma unroll
            for (int mi = 0; mi < 4; mi++) {
                float4 v0 = *(const float4*)(ar[mi] + k0);
                float4 v1 = *(const float4*)(ar[mi] + k0 + 4);
                bf16x8 t8 = { f2bf(v0.x), f2bf(v0.y), f2bf(v0.z), f2bf(v0.w),
                              f2bf(v1.x), f2bf(v1.y), f2bf(v1.z), f2bf(v1.w) };
                af[mi] = t8;
            }
            #pragma unroll
            for (int ni = 0; ni < 4; ni++) bfr[ni] = *(const bf16x8*)(br[ni] + k0);
            #pragma unroll
            for (int mi = 0; mi < 4; mi++)
                #pragma unroll
                for (int ni = 0; ni < 4; ni++)
                    acc[mi][ni] = __builtin_amdgcn_mfma_f32_16x16x32_bf16(
                        af[mi], bfr[ni], acc[mi][ni], 0, 0, 0);
        }
        float bv[4];
        #pragma unroll
        for (int ni = 0; ni < 4; ni++) bv[ni] = bq[n0 + ni * 16 + lc];
        // Epilogue: write X and XT; pad rows (t >= 49) get ZEROS -> masked
        // softmax paths are NaN-free and S pad rows/cols are exactly 0.
        #pragma unroll
        for (int mi = 0; mi < 4; mi++)
            #pragma unroll
            for (int rg = 0; rg < 4; rg++) {
                const int t = mi * 16 + lq * 4 + rg;
                #pragma unroll
                for (int ni = 0; ni < 4; ni++) {
                    const int col = n0 + ni * 16 + lc;
                    const short s = (t < WW) ? f2bf(acc[mi][ni][rg] + bv[ni])
                                             : (short)0;
                    sm[qix(t, col)] = s;
                    sm[tix(col, t)] = s;
                }
            }
    }
    __syncthreads();

    // ================= Phase 2: attention, one wave per head ==============
    // Wave wv owns head wv: X cols [c0, c0+64). Barrier-free: S reads only
    // this slice; P overwrites this slice (dead after S); O overwrites P
    // (a-frags register-loaded before the stores; same-wave LDS order).
    {
        const int c0 = n0;
        bf16x8 xa[4][2];
        #pragma unroll
        for (int mi = 0; mi < 4; mi++) {
            xa[mi][0] = *(const bf16x8*)&sm[qix(mi * 16 + lc, c0 + lq * 8)];
            xa[mi][1] = *(const bf16x8*)&sm[qix(mi * 16 + lc, c0 + 32 + lq * 8)];
        }
        f32x4 sa[4][4] = {};
        #pragma unroll
        for (int mi = 0; mi < 4; mi++)
            #pragma unroll
            for (int ni = 0; ni < 4; ni++) {
                sa[mi][ni] = __builtin_amdgcn_mfma_f32_16x16x32_bf16(
                    xa[mi][0], xa[ni][0], sa[mi][ni], 0, 0, 0);
                sa[mi][ni] = __builtin_amdgcn_mfma_f32_16x16x32_bf16(
                    xa[mi][1], xa[ni][1], sa[mi][ni], 0, 0, 0);
            }
        // softmax rows; P (bf16) written over X[:, c0:c0+64)
        #pragma unroll
        for (int mi = 0; mi < 4; mi++)
            #pragma unroll
            for (int rg = 0; rg < 4; rg++) {
                float s[4];
                float m = -1e30f;
                #pragma unroll
                for (int ni = 0; ni < 4; ni++) {
                    s[ni] = sa[mi][ni][rg] * 0.125f;      // 1/sqrt(64)
                    if (ni * 16 + lc < WW) m = fmaxf(m, s[ni]);
                }
                m = fmaxf(m, __shfl_xor(m, 1));
                m = fmaxf(m, __shfl_xor(m, 2));
                m = fmaxf(m, __shfl_xor(m, 4));
                m = fmaxf(m, __shfl_xor(m, 8));
                float e4[4], l_ = 0.f;
                #pragma unroll
                for (int ni = 0; ni < 4; ni++) {
                    e4[ni] = (ni * 16 + lc < WW) ? __expf(s[ni] - m) : 0.f;
                    l_ += e4[ni];
                }
                l_ += __shfl_xor(l_, 1);
                l_ += __shfl_xor(l_, 2);
                l_ += __shfl_xor(l_, 4);
                l_ += __shfl_xor(l_, 8);
                const float inv = 1.f / l_;
                const int i = mi * 16 + lq * 4 + rg;
                #pragma unroll
                for (int ni = 0; ni < 4; ni++)
                    sm[qix(i, c0 + ni * 16 + lc)] = f2bf(e4[ni] * inv);
            }
        // O = P (from X slice) · X (from XT slice)
        bf16x8 pa[4][2], pb[4][2];
        #pragma unroll
        for (int mi = 0; mi < 4; mi++) {
            pa[mi][0] = *(const bf16x8*)&sm[qix(mi * 16 + lc, c0 + lq * 8)];
            pa[mi][1] = *(const bf16x8*)&sm[qix(mi * 16 + lc, c0 + 32 + lq * 8)];
        }
        #pragma unroll
        for (int ni = 0; ni < 4; ni++) {
            pb[ni][0] = *(const bf16x8*)&sm[tix(c0 + ni * 16 + lc, lq * 8)];
            pb[ni][1] = *(const bf16x8*)&sm[tix(c0 + ni * 16 + lc, 32 + lq * 8)];
        }
        f32x4 oa[4][4] = {};
        #pragma unroll
        for (int mi = 0; mi < 4; mi++)
            #pragma unroll
            for (int ni = 0; ni < 4; ni++) {
                oa[mi][ni] = __builtin_amdgcn_mfma_f32_16x16x32_bf16(
                    pa[mi][0], pb[ni][0], oa[mi][ni], 0, 0, 0);
                oa[mi][ni] = __builtin_amdgcn_mfma_f32_16x16x32_bf16(
                    pa[mi][1], pb[ni][1], oa[mi][ni], 0, 0, 0);
            }
        // O overwrites P in X[:, c0:c0+64). Rows >= 49 keep benign P values.
        #pragma unroll
        for (int mi = 0; mi < 4; mi++)
            #pragma unroll
            for (int rg = 0; rg < 4; rg++) {
                const int i = mi * 16 + lq * 4 + rg;
                if (i < WW) {
                    #pragma unroll
                    for (int ni = 0; ni < 4; ni++)
                        sm[qix(i, c0 + ni * 16 + lc)] = f2bf(oa[mi][ni][rg]);
                }
            }
    }
    __syncthreads();

    // ================= Phase 3: out = O @ Wo^T + bo =======================
    {
        const short* br[4];
        #pragma unroll
        for (int ni = 0; ni < 4; ni++)
            br[ni] = Wob + (size_t)(n0 + ni * 16 + lc) * DM + lq * 8;
        int trow[4];
        #pragma unroll
        for (int mi = 0; mi < 4; mi++) {
            int t = mi * 16 + lc;
            trow[mi] = (t > WW - 1) ? (WW - 1) : t;       // avoid stale pad rows
        }
        f32x4 acc[4][4] = {};
        for (int k0 = 0; k0 < DM; k0 += 32) {
            bf16x8 af[4], bfr[4];
            #pragma unroll
            for (int mi = 0; mi < 4; mi++)
                af[mi] = *(const bf16x8*)&sm[qix(trow[mi], k0 + lq * 8)];
            #pragma unroll
            for (int ni = 0; ni < 4; ni++) bfr[ni] = *(const bf16x8*)(br[ni] + k0);
            #pragma unroll
            for (int mi = 0; mi < 4; mi++)
                #pragma unroll
                for (int ni = 0; ni < 4; ni++)
                    acc[mi][ni] = __builtin_amdgcn_mfma_f32_16x16x32_bf16(
                        af[mi], bfr[ni], acc[mi][ni], 0, 0, 0);
        }
        float bv[4];
        #pragma unroll
        for (int ni = 0; ni < 4; ni++) bv[ni] = bo[n0 + ni * 16 + lc];
        #pragma unroll
        for (int mi = 0; mi < 4; mi++)
            #pragma unroll
            for (int rg = 0; rg < 4; rg++) {
                const int t = mi * 16 + lq * 4 + rg;
                if (t < WW) {
                    float* op = out + (tok0 + (size_t)t * RD) * DM + n0;
                    #pragma unroll
                    for (int ni = 0; ni < 4; ni++)
                        op[ni * 16 + lc] = acc[mi][ni][rg] + bv[ni];
                }
            }
    }
}

// ---------------------------------------------------------------------------
extern "C" void kernel_launch(void* const* d_in, const int* in_sizes, int n_in,
                              void* d_out, int out_size, void* d_ws, size_t ws_size,
                              hipStream_t stream) {
    const float* emb = (const float*)d_in[0];
    const float* Wq  = (const float*)d_in[1];
    const float* bq  = (const float*)d_in[2];
    const float* Wo  = (const float*)d_in[3];
    const float* bo  = (const float*)d_in[4];
    float* out = (float*)d_out;

    // Workspace: Wq bf16 (128 KB) | Wo bf16 (128 KB)
    short* Wqb = (short*)d_ws;
    short* Wob = Wqb + DM * DM;

    wcvt<<<dim3(128), dim3(256), 0, stream>>>(Wq, Wo, Wqb, Wob);
    fused<<<dim3(BATCH * GSEG * RD), dim3(256), 0, stream>>>(
        emb, Wqb, bq, Wob, bo, out);
}